// Round 2
// baseline (311.784 us; speedup 1.0000x reference)
//
#include <hip/hip_runtime.h>

// EdgeScoringNetwork on MI355X (gfx950).
//   nf = l2norm(node_feat); per edge: ef=[hs,ht,dist] -> relu(W1 ef+b1) -> relu(W2 h+b2) -> W3 h+b3
//   out[0..E)   = clip(sigmoid(logA)*1.2-0.1, 0,1)
//   out[E..2E)  = logA
// Strategy: split-bf16 (hi+lo) MFMA 16x16x32, A-frags gathered directly from a packed
// (lo<<16|hi) node-feature table, B-frags pre-laid-out in fragment order and LDS-staged.
// ws layout: [nfp 25.6MB][B1hi 64K][B1lo 64K][B2hi 32K][B2lo 32K]  (~24.6 MiB total)

#define E_TOT 600000
#define NN    50000
#define DIN   128

typedef short bf16x8 __attribute__((ext_vector_type(8)));
typedef float f32x4  __attribute__((ext_vector_type(4)));

union FragU { uint4 q; unsigned int u[4]; bf16x8 v; };

__device__ __forceinline__ unsigned int f2bf(float x) {
  // RNE fp32 -> bf16 bits (finite inputs only)
  unsigned int b = __float_as_uint(x);
  return ((b + 0x7fffu + ((b >> 16) & 1u)) >> 16) & 0xffffu;
}
__device__ __forceinline__ unsigned int packsplit(float x) {
  // packed split-bf16: low16 = bf16(x), high16 = bf16(x - hi)
  unsigned int hi = f2bf(x);
  float lo = x - __uint_as_float(hi << 16);
  return hi | (f2bf(lo) << 16);
}

// ---------------- kernel 1: L2-normalize nodes, emit packed split-bf16 ----------------
__global__ __launch_bounds__(256) void k_norm(const float* __restrict__ nf,
                                              unsigned int* __restrict__ nfp) {
  const int wv = threadIdx.x >> 6, l = threadIdx.x & 63;
  const int node = blockIdx.x * 4 + wv;           // 12500 * 4 = 50000 exactly
  const float2* row = (const float2*)(nf + (size_t)node * DIN);
  float2 v = row[l];
  float ss = v.x * v.x + v.y * v.y;
  #pragma unroll
  for (int m = 1; m < 64; m <<= 1) ss += __shfl_xor(ss, m);
  const float inv = 1.0f / (sqrtf(ss) + 1e-8f);   // matches reference: x/(norm+1e-8)
  uint2 o; o.x = packsplit(v.x * inv); o.y = packsplit(v.y * inv);
  ((uint2*)(nfp + (size_t)node * DIN))[l] = o;
}

// ---------------- kernel 2: weights -> MFMA B-fragment layout (hi/lo) ----------------
// B1 frag id = ((s*8+nt)*64+lane)*4+dw : elems k=8*(lane>>4)+32*s+2*dw(+1), n=16*nt+(lane&15)
__global__ __launch_bounds__(256) void k_prep(const float* __restrict__ W1,
                                              const float* __restrict__ W2,
                                              unsigned int* __restrict__ B1hi,
                                              unsigned int* __restrict__ B1lo,
                                              unsigned int* __restrict__ B2hi,
                                              unsigned int* __restrict__ B2lo) {
  const int id = blockIdx.x * 256 + threadIdx.x;  // 96*256 = 24576
  if (id < 16384) {
    const int dw = id & 3, lane = (id >> 2) & 63, nt = (id >> 8) & 7, s = id >> 11;
    const int n = nt * 16 + (lane & 15);
    const int k0 = (lane >> 4) * 8 + s * 32 + dw * 2;
    const float v0 = W1[n * 257 + k0], v1 = W1[n * 257 + k0 + 1];
    unsigned int h0 = f2bf(v0), h1 = f2bf(v1);
    float l0 = v0 - __uint_as_float(h0 << 16), l1 = v1 - __uint_as_float(h1 << 16);
    B1hi[id] = h0 | (h1 << 16);
    B1lo[id] = f2bf(l0) | (f2bf(l1) << 16);
  } else {
    const int i2 = id - 16384;                    // < 8192
    const int dw = i2 & 3, lane = (i2 >> 2) & 63, nt = (i2 >> 8) & 7, s = i2 >> 11;
    const int n = nt * 16 + (lane & 15);
    const int k0 = (lane >> 4) * 8 + s * 32 + dw * 2;
    const float v0 = W2[n * 128 + k0], v1 = W2[n * 128 + k0 + 1];
    unsigned int h0 = f2bf(v0), h1 = f2bf(v1);
    float l0 = v0 - __uint_as_float(h0 << 16), l1 = v1 - __uint_as_float(h1 << 16);
    B2hi[i2] = h0 | (h1 << 16);
    B2lo[i2] = f2bf(l0) | (f2bf(l1) << 16);
  }
}

// ---------------- kernel 3: fused edge MLP ----------------
// block = 256 (4 waves), wave = 16 edges, grid = 9375 (exactly 600000 edges).
// LDS: [0..2047] B-hi chunk, [2048..4095] B-lo chunk, then 4 per-wave h1 tiles 16x132 uints.
__global__ __launch_bounds__(256, 2) void k_main(
    const unsigned int* __restrict__ nfp, const int* __restrict__ ei,
    const unsigned int* __restrict__ B1hi, const unsigned int* __restrict__ B1lo,
    const unsigned int* __restrict__ B2hi, const unsigned int* __restrict__ B2lo,
    const float* __restrict__ W1, const float* __restrict__ b1,
    const float* __restrict__ b2, const float* __restrict__ W3,
    const float* __restrict__ b3, float* __restrict__ out) {
  __shared__ unsigned int lds[4096 + 4 * 2112];   // 50,176 B
  const int tid = threadIdx.x;
  const int wv = tid >> 6, l = tid & 63, m = l & 15, a = l >> 4;
  unsigned int* sH = lds + 4096 + wv * 2112;      // this wave's h1 tile, stride 132

  // --- edge_index dtype defense: if the harness kept int64, every odd 32-bit word
  // of the first 32 values is a zero high-word (node ids < 50000). P(false positive
  // with genuine int32 data) ~ (1/50000)^32 ~ 0.
  bool is64 = true;
  #pragma unroll
  for (int w = 1; w < 64; w += 2) is64 = is64 && (ei[w] == 0);

  const int e  = blockIdx.x * 64 + wv * 16 + m;   // edge this lane gathers (A-row m)
  const int ec = min(e, E_TOT - 1);
  int nsrc, ntgt;
  if (is64) { nsrc = ei[2 * ec]; ntgt = ei[2 * (E_TOT + ec)]; }
  else      { nsrc = ei[ec];     ntgt = ei[E_TOT + ec]; }
  // degrade-to-wrong-values (not OOB fault) if dtype detection ever mis-fires
  nsrc = min(max(nsrc, 0), NN - 1);
  ntgt = min(max(ntgt, 0), NN - 1);

  // --- gather A directly in fragment order: lane l holds dims 8a+32s+j of edge m
  const uint4* rs = (const uint4*)(nfp + (size_t)nsrc * DIN);
  const uint4* rt = (const uint4*)(nfp + (size_t)ntgt * DIN);
  uint4 hsv[8], htv[8];                           // [2s+q], q selects dwords 0..3 / 4..7
  #pragma unroll
  for (int s = 0; s < 4; ++s) {
    hsv[2 * s]     = rs[2 * a + 8 * s];
    hsv[2 * s + 1] = rs[2 * a + 8 * s + 1];
    htv[2 * s]     = rt[2 * a + 8 * s];
    htv[2 * s + 1] = rt[2 * a + 8 * s + 1];
  }

  // --- dist = ||hs-ht||, fp32 from split values; each lane owns 32 dims of edge m
  float dp = 0.f;
  #pragma unroll
  for (int i = 0; i < 8; ++i) {
    const unsigned int* hu = (const unsigned int*)&hsv[i];
    const unsigned int* tu = (const unsigned int*)&htv[i];
    #pragma unroll
    for (int j = 0; j < 4; ++j) {
      float hv = __uint_as_float(hu[j] << 16) + __uint_as_float(hu[j] & 0xffff0000u);
      float tv = __uint_as_float(tu[j] << 16) + __uint_as_float(tu[j] & 0xffff0000u);
      float d = hv - tv;
      dp = fmaf(d, d, dp);
    }
  }
  dp += __shfl_xor(dp, 16);
  dp += __shfl_xor(dp, 32);
  const float dist = sqrtf(dp);                   // lives on lanes with l&15 == edge
  float dist_r[4];                                // re-shuffled to C-layout rows 4a+r
  #pragma unroll
  for (int r = 0; r < 4; ++r) dist_r[r] = __shfl(dist, a * 4 + r);

  // --- per-lane weight columns (n = 16*nt + m)
  float b1v[8], w1l[8], b2v[8], w3v[8];
  #pragma unroll
  for (int nt = 0; nt < 8; ++nt) {
    const int n = nt * 16 + m;
    b1v[nt] = b1[n];
    w1l[nt] = W1[n * 257 + 256];                  // dist column of W1
    b2v[nt] = b2[n];
    w3v[nt] = W3[n];
  }
  const float b3v = b3[0];
  #pragma unroll
  for (int nt = 0; nt < 8; ++nt)                  // force materialization before the loop
    asm volatile("" :: "v"(b1v[nt]), "v"(w1l[nt]), "v"(b2v[nt]), "v"(w3v[nt]));

  f32x4 acc[8];
  #pragma unroll
  for (int nt = 0; nt < 8; ++nt) acc[nt] = (f32x4){0.f, 0.f, 0.f, 0.f};

  // --- B staging: chunk = 2048 dwords (8KB hi + 8KB lo per step), 256 threads x 2 uint4
  const uint4* g1h = (const uint4*)B1hi; const uint4* g1l = (const uint4*)B1lo;
  const uint4* g2h = (const uint4*)B2hi; const uint4* g2l = (const uint4*)B2lo;
  uint4* sBh = (uint4*)lds;                       // 512 uint4
  uint4* sBl = (uint4*)(lds + 2048);
  uint4 nh0 = g1h[tid], nh1 = g1h[tid + 256];
  uint4 nl0 = g1l[tid], nl1 = g1l[tid + 256];

  #pragma unroll
  for (int st = 0; st < 12; ++st) {
    __syncthreads();                              // prior step's B reads complete
    sBh[tid] = nh0; sBh[tid + 256] = nh1;
    sBl[tid] = nl0; sBl[tid + 256] = nl1;
    __syncthreads();                              // chunk visible
    if (st < 11) {                                // prefetch next chunk; latency hides
      const int s2 = st + 1;                      // under this step's compute
      if (s2 < 8) { nh0 = g1h[s2 * 512 + tid]; nh1 = g1h[s2 * 512 + tid + 256];
                    nl0 = g1l[s2 * 512 + tid]; nl1 = g1l[s2 * 512 + tid + 256]; }
      else        { const int s3 = s2 - 8;
                    nh0 = g2h[s3 * 512 + tid]; nh1 = g2h[s3 * 512 + tid + 256];
                    nl0 = g2l[s3 * 512 + tid]; nl1 = g2l[s3 * 512 + tid + 256]; }
    }

    // A fragment for this K-step
    FragU ahi, alo;
    uint4 q0, q1;
    if (st < 8) {
      q0 = (st < 4) ? hsv[2 * st] : htv[2 * (st - 4)];
      q1 = (st < 4) ? hsv[2 * st + 1] : htv[2 * (st - 4) + 1];
    } else {
      const int s2 = st - 8;                      // h1 from this wave's LDS tile
      const uint4* h4 = (const uint4*)sH;
      q0 = h4[m * 33 + 2 * a + 8 * s2];
      q1 = h4[m * 33 + 2 * a + 8 * s2 + 1];
    }
    ahi.u[0] = __builtin_amdgcn_perm(q0.y, q0.x, 0x05040100u);
    ahi.u[1] = __builtin_amdgcn_perm(q0.w, q0.z, 0x05040100u);
    ahi.u[2] = __builtin_amdgcn_perm(q1.y, q1.x, 0x05040100u);
    ahi.u[3] = __builtin_amdgcn_perm(q1.w, q1.z, 0x05040100u);
    alo.u[0] = __builtin_amdgcn_perm(q0.y, q0.x, 0x07060302u);
    alo.u[1] = __builtin_amdgcn_perm(q0.w, q0.z, 0x07060302u);
    alo.u[2] = __builtin_amdgcn_perm(q1.y, q1.x, 0x07060302u);
    alo.u[3] = __builtin_amdgcn_perm(q1.w, q1.z, 0x07060302u);

    #pragma unroll
    for (int nt = 0; nt < 8; ++nt) {
      FragU bh, bl;
      bh.q = sBh[nt * 64 + l];
      bl.q = sBl[nt * 64 + l];
      acc[nt] = __builtin_amdgcn_mfma_f32_16x16x32_bf16(ahi.v, bh.v, acc[nt], 0, 0, 0);
      acc[nt] = __builtin_amdgcn_mfma_f32_16x16x32_bf16(alo.v, bh.v, acc[nt], 0, 0, 0);
      acc[nt] = __builtin_amdgcn_mfma_f32_16x16x32_bf16(ahi.v, bl.v, acc[nt], 0, 0, 0);
    }

    if (st == 7) {                                // h1 epilogue -> per-wave LDS tile
      #pragma unroll
      for (int nt = 0; nt < 8; ++nt) {
        #pragma unroll
        for (int r = 0; r < 4; ++r) {
          float v = acc[nt][r] + b1v[nt] + w1l[nt] * dist_r[r];
          v = fmaxf(v, 0.f);
          sH[(a * 4 + r) * 132 + nt * 16 + m] = packsplit(v);
        }
        acc[nt] = (f32x4){0.f, 0.f, 0.f, 0.f};    // reuse as GEMM2 accumulator
      }
    }
  }

  // --- layer 3 + gate
  float part[4] = {0.f, 0.f, 0.f, 0.f};
  #pragma unroll
  for (int nt = 0; nt < 8; ++nt)
    #pragma unroll
    for (int r = 0; r < 4; ++r) {
      const float h2 = fmaxf(acc[nt][r] + b2v[nt], 0.f);
      part[r] = fmaf(h2, w3v[nt], part[r]);
    }
  #pragma unroll
  for (int r = 0; r < 4; ++r) {
    part[r] += __shfl_xor(part[r], 1);
    part[r] += __shfl_xor(part[r], 2);
    part[r] += __shfl_xor(part[r], 4);
    part[r] += __shfl_xor(part[r], 8);
  }
  if (m == 0) {
    #pragma unroll
    for (int r = 0; r < 4; ++r) {
      const int eo = blockIdx.x * 64 + wv * 16 + a * 4 + r;
      const float la = part[r] + b3v;
      const float sg = 1.f / (1.f + __expf(-la));
      out[eo] = fminf(fmaxf(sg * 1.2f - 0.1f, 0.f), 1.f);
      out[E_TOT + eo] = la;
    }
  }
}

extern "C" void kernel_launch(void* const* d_in, const int* in_sizes, int n_in,
                              void* d_out, int out_size, void* d_ws, size_t ws_size,
                              hipStream_t stream) {
  const float* node_feat = (const float*)d_in[0];
  const int*   edge_idx  = (const int*)d_in[1];
  const float* W1 = (const float*)d_in[2];
  const float* b1 = (const float*)d_in[3];
  const float* W2 = (const float*)d_in[4];
  const float* b2 = (const float*)d_in[5];
  const float* W3 = (const float*)d_in[6];
  const float* b3 = (const float*)d_in[7];
  float* out = (float*)d_out;

  unsigned char* ws = (unsigned char*)d_ws;
  // requires ws_size >= 25,796,608 bytes
  unsigned int* nfp  = (unsigned int*)(ws);
  unsigned int* B1hi = (unsigned int*)(ws + 25600000);
  unsigned int* B1lo = (unsigned int*)(ws + 25600000 + 65536);
  unsigned int* B2hi = (unsigned int*)(ws + 25600000 + 131072);
  unsigned int* B2lo = (unsigned int*)(ws + 25600000 + 163840);

  hipLaunchKernelGGL(k_norm, dim3(12500), dim3(256), 0, stream, node_feat, nfp);
  hipLaunchKernelGGL(k_prep, dim3(96), dim3(256), 0, stream, W1, W2, B1hi, B1lo, B2hi, B2lo);
  hipLaunchKernelGGL(k_main, dim3(9375), dim3(256), 0, stream,
                     nfp, edge_idx, B1hi, B1lo, B2hi, B2lo, W1, b1, b2, W3, b3, out);
}

// Round 3
// 202.151 us; speedup vs baseline: 1.5423x; 1.5423x over previous
//
#include <hip/hip_runtime.h>

// EdgeScoringNetwork on MI355X (gfx950) — plain-bf16 MFMA version.
//   nf = l2norm(node_feat); per edge: ef=[hs,ht,dist] -> relu(W1 ef+b1) -> relu(W2 h+b2) -> W3 h+b3
//   out[0..E) = clip(sigmoid(logA)*1.2-0.1, 0,1);  out[E..2E) = logA
// R3 change vs R2: drop split-bf16 (3 MFMA -> 1), plain bf16 node table (256B rows),
// 8KB/step B staging, bf16 h1 tile with XOR-swizzle, occupancy 12 -> 16 waves/CU.
// ws layout: [nfb 12.8MB][B1 64KB][B2 32KB]

#define E_TOT 600000
#define NN    50000
#define DIN   128

typedef short bf16x8 __attribute__((ext_vector_type(8)));
typedef float f32x4  __attribute__((ext_vector_type(4)));

union FragU { uint4 q; unsigned int u[4]; bf16x8 v; };

__device__ __forceinline__ unsigned int f2bf(float x) {
  // RNE fp32 -> bf16 bits (finite inputs only)
  unsigned int b = __float_as_uint(x);
  return ((b + 0x7fffu + ((b >> 16) & 1u)) >> 16) & 0xffffu;
}

// ---------------- kernel 1: L2-normalize nodes -> plain bf16 rows ----------------
// 2 nodes per wave (32 lanes x float4 = 128 dims), 8 nodes/block, grid 6250.
__global__ __launch_bounds__(256) void k_norm(const float* __restrict__ nf,
                                              unsigned short* __restrict__ nfb) {
  const int wv = threadIdx.x >> 6, l = threadIdx.x & 63;
  const int h = l >> 5, r = l & 31;
  const int node = blockIdx.x * 8 + wv * 2 + h;    // 6250*8 = 50000 exactly
  const float4* row = (const float4*)(nf + (size_t)node * DIN);
  float4 v = row[r];
  float ss = v.x * v.x + v.y * v.y + v.z * v.z + v.w * v.w;
  #pragma unroll
  for (int msk = 1; msk < 32; msk <<= 1) ss += __shfl_xor(ss, msk);
  const float inv = 1.0f / (sqrtf(ss) + 1e-8f);    // matches reference x/(norm+1e-8)
  uint2 o;
  o.x = f2bf(v.x * inv) | (f2bf(v.y * inv) << 16);
  o.y = f2bf(v.z * inv) | (f2bf(v.w * inv) << 16);
  ((uint2*)(nfb + (size_t)node * DIN))[r] = o;
}

// ---------------- kernel 2: weights -> MFMA B-fragment layout (bf16) ----------------
// frag dword id = ((s*8+nt)*64+lane)*4+dw : k=8*(lane>>4)+32*s+2*dw(+1), n=16*nt+(lane&15)
__global__ __launch_bounds__(256) void k_prep(const float* __restrict__ W1,
                                              const float* __restrict__ W2,
                                              unsigned int* __restrict__ B1,
                                              unsigned int* __restrict__ B2) {
  const int id = blockIdx.x * 256 + threadIdx.x;   // 96*256 = 24576
  if (id < 16384) {                                // B1: 8 K-steps (K=256)
    const int dw = id & 3, lane = (id >> 2) & 63, nt = (id >> 8) & 7, s = id >> 11;
    const int n = nt * 16 + (lane & 15);
    const int k0 = (lane >> 4) * 8 + s * 32 + dw * 2;
    B1[id] = f2bf(W1[n * 257 + k0]) | (f2bf(W1[n * 257 + k0 + 1]) << 16);
  } else {                                         // B2: 4 K-steps (K=128), 8192 dwords
    const int i2 = id - 16384;
    const int dw = i2 & 3, lane = (i2 >> 2) & 63, nt = (i2 >> 8) & 7, s = i2 >> 11;
    const int n = nt * 16 + (lane & 15);
    const int k0 = (lane >> 4) * 8 + s * 32 + dw * 2;
    B2[i2] = f2bf(W2[n * 128 + k0]) | (f2bf(W2[n * 128 + k0 + 1]) << 16);
  }
}

// ---------------- kernel 3: fused edge MLP ----------------
// block = 256 (4 waves), wave = 16 edges, grid = 9375 (exactly 600000 edges).
// LDS: [0..2047] B chunk (8KB), then 4 per-wave h1 tiles 16x128 bf16 (4KB each, XOR-swizzled).
__global__ __launch_bounds__(256, 4) void k_main(
    const unsigned short* __restrict__ nfb, const int* __restrict__ ei,
    const unsigned int* __restrict__ B1, const unsigned int* __restrict__ B2,
    const float* __restrict__ W1, const float* __restrict__ b1,
    const float* __restrict__ b2, const float* __restrict__ W3,
    const float* __restrict__ b3, float* __restrict__ out) {
  __shared__ unsigned int lds[2048 + 4 * 1024];    // 24,576 B total
  const int tid = threadIdx.x;
  const int wv = tid >> 6, l = tid & 63, m = l & 15, a = l >> 4;
  char* sHb = (char*)(lds + 2048) + wv * 4096;     // this wave's h1 tile (bytes)

  // --- edge_index dtype defense (int64 -> odd 32-bit words are zero high-words)
  bool is64 = true;
  #pragma unroll
  for (int w = 1; w < 64; w += 2) is64 = is64 && (ei[w] == 0);

  const int e = blockIdx.x * 64 + wv * 16 + m;     // < 600000 always (exact grid)
  int nsrc, ntgt;
  if (is64) { nsrc = ei[2 * e]; ntgt = ei[2 * (E_TOT + e)]; }
  else      { nsrc = ei[e];     ntgt = ei[E_TOT + e]; }
  nsrc = min(max(nsrc, 0), NN - 1);                // degrade, don't fault
  ntgt = min(max(ntgt, 0), NN - 1);

  // --- gather A-frags directly: lane (a,m) holds dims {8a+32s+j} of edge m (8 bf16 = uint4)
  const uint4* rs = (const uint4*)(nfb + (size_t)nsrc * DIN);  // 16 uint4 per row
  const uint4* rt = (const uint4*)(nfb + (size_t)ntgt * DIN);
  uint4 hsv[4], htv[4];
  #pragma unroll
  for (int s = 0; s < 4; ++s) { hsv[s] = rs[a + 4 * s]; htv[s] = rt[a + 4 * s]; }

  // --- dist = ||hs-ht|| in fp32 from the bf16 values; each lane owns 32 dims of edge m
  float dp = 0.f;
  #pragma unroll
  for (int i = 0; i < 4; ++i) {
    const unsigned int* hu = (const unsigned int*)&hsv[i];
    const unsigned int* tu = (const unsigned int*)&htv[i];
    #pragma unroll
    for (int j = 0; j < 4; ++j) {
      float h0 = __uint_as_float(hu[j] << 16), t0 = __uint_as_float(tu[j] << 16);
      float h1v = __uint_as_float(hu[j] & 0xffff0000u), t1v = __uint_as_float(tu[j] & 0xffff0000u);
      float d0 = h0 - t0, d1 = h1v - t1v;
      dp = fmaf(d0, d0, dp);
      dp = fmaf(d1, d1, dp);
    }
  }
  dp += __shfl_xor(dp, 16);
  dp += __shfl_xor(dp, 32);
  const float dist = sqrtf(dp);
  float dist_r[4];                                 // C-layout rows 4a+r need dist[4a+r]
  #pragma unroll
  for (int r = 0; r < 4; ++r) dist_r[r] = __shfl(dist, a * 4 + r);

  f32x4 acc[8];
  #pragma unroll
  for (int nt = 0; nt < 8; ++nt) acc[nt] = (f32x4){0.f, 0.f, 0.f, 0.f};

  // --- B staging: 8KB/step (512 uint4), 256 threads x 2 uint4, register-prefetched
  const uint4* g1 = (const uint4*)B1;              // 4096 uint4 (8 steps)
  const uint4* g2 = (const uint4*)B2;              // 2048 uint4 (4 steps)
  uint4* sB = (uint4*)lds;
  uint4 n0 = g1[tid], n1 = g1[tid + 256];

  #pragma unroll
  for (int st = 0; st < 12; ++st) {
    __syncthreads();                               // prior step's B reads complete
    sB[tid] = n0; sB[tid + 256] = n1;
    __syncthreads();                               // chunk visible
    if (st < 11) {                                 // prefetch next; hides under compute
      const int s2 = st + 1;
      if (s2 < 8) { n0 = g1[s2 * 512 + tid]; n1 = g1[s2 * 512 + tid + 256]; }
      else        { const int s3 = s2 - 8;
                    n0 = g2[s3 * 512 + tid]; n1 = g2[s3 * 512 + tid + 256]; }
    }

    FragU af;
    if (st < 4)      af.q = hsv[st];
    else if (st < 8) af.q = htv[st - 4];
    else {                                         // h1 A-frag from swizzled LDS tile
      const int s2 = st - 8;
      const int col = 16 * a + 64 * s2;            // byte col = (8a+32s)*2
      af.q = *(const uint4*)(sHb + m * 256 + (col ^ ((m & 7) << 4)));
    }

    #pragma unroll
    for (int nt = 0; nt < 8; ++nt) {
      FragU bfr; bfr.q = sB[nt * 64 + l];
      acc[nt] = __builtin_amdgcn_mfma_f32_16x16x32_bf16(af.v, bfr.v, acc[nt], 0, 0, 0);
    }

    if (st == 7) {                                 // h1 epilogue -> swizzled bf16 tile
      #pragma unroll
      for (int nt = 0; nt < 8; ++nt) {
        const int n = nt * 16 + m;
        const float b1v = b1[n];
        const float w1l = W1[n * 257 + 256];       // dist column of W1
        #pragma unroll
        for (int r = 0; r < 4; ++r) {
          const int row = 4 * a + r;
          float v = acc[nt][r] + b1v + w1l * dist_r[r];
          v = fmaxf(v, 0.f);
          *(unsigned short*)(sHb + row * 256 + ((n * 2) ^ ((row & 7) << 4))) =
              (unsigned short)f2bf(v);
        }
        acc[nt] = (f32x4){0.f, 0.f, 0.f, 0.f};     // reuse as GEMM2 accumulator
      }
    }
  }

  // --- layer 3 + gate
  float part[4] = {0.f, 0.f, 0.f, 0.f};
  #pragma unroll
  for (int nt = 0; nt < 8; ++nt) {
    const int n = nt * 16 + m;
    const float b2v = b2[n];
    const float w3v = W3[n];
    #pragma unroll
    for (int r = 0; r < 4; ++r) {
      const float h2 = fmaxf(acc[nt][r] + b2v, 0.f);
      part[r] = fmaf(h2, w3v, part[r]);
    }
  }
  #pragma unroll
  for (int r = 0; r < 4; ++r) {
    part[r] += __shfl_xor(part[r], 1);
    part[r] += __shfl_xor(part[r], 2);
    part[r] += __shfl_xor(part[r], 4);
    part[r] += __shfl_xor(part[r], 8);
  }
  if (m == 0) {
    const float b3v = b3[0];
    #pragma unroll
    for (int r = 0; r < 4; ++r) {
      const int eo = blockIdx.x * 64 + wv * 16 + a * 4 + r;
      const float la = part[r] + b3v;
      const float sg = 1.f / (1.f + __expf(-la));
      out[eo] = fminf(fmaxf(sg * 1.2f - 0.1f, 0.f), 1.f);
      out[E_TOT + eo] = la;
    }
  }
}

extern "C" void kernel_launch(void* const* d_in, const int* in_sizes, int n_in,
                              void* d_out, int out_size, void* d_ws, size_t ws_size,
                              hipStream_t stream) {
  const float* node_feat = (const float*)d_in[0];
  const int*   edge_idx  = (const int*)d_in[1];
  const float* W1 = (const float*)d_in[2];
  const float* b1 = (const float*)d_in[3];
  const float* W2 = (const float*)d_in[4];
  const float* b2 = (const float*)d_in[5];
  const float* W3 = (const float*)d_in[6];
  const float* b3 = (const float*)d_in[7];
  float* out = (float*)d_out;

  unsigned char* ws = (unsigned char*)d_ws;
  // requires ws_size >= 12,898,304 bytes
  unsigned short* nfb = (unsigned short*)(ws);                       // 12.8 MB
  unsigned int*   B1  = (unsigned int*)(ws + 12800000);              // 64 KB
  unsigned int*   B2  = (unsigned int*)(ws + 12800000 + 65536);      // 32 KB

  hipLaunchKernelGGL(k_norm, dim3(6250), dim3(256), 0, stream, node_feat, nfb);
  hipLaunchKernelGGL(k_prep, dim3(96), dim3(256), 0, stream, W1, W2, B1, B2);
  hipLaunchKernelGGL(k_main, dim3(9375), dim3(256), 0, stream,
                     nfb, edge_idx, B1, B2, W1, b1, b2, W3, b3, out);
}

// Round 6
// 191.571 us; speedup vs baseline: 1.6275x; 1.0552x over previous
//
#include <hip/hip_runtime.h>

// EdgeScoringNetwork on MI355X (gfx950) — bf16 MFMA, 32 edges/wave.
//   nf = l2norm(node_feat); per edge: ef=[hs,ht,dist] -> relu(W1 ef+b1) -> relu(W2 h+b2) -> W3 h+b3
//   out[0..E) = clip(sigmoid(logA)*1.2-0.1, 0,1);  out[E..2E) = logA
// R6 == R4/R5 (never benched: GPU timeouts). Two 16-edge M-tiles per wave share every weight
// B-frag read (weight-LDS/edge halves vs R3); weight staging via global_load_lds width=16,
// double-buffered, 1 barrier/step; k_prep fused into k_norm. Per-edge numerics == R3.
// ws layout: [nfb 12.8MB][B1 64KB][B2 32KB]

#define E_TOT 600000
#define NN    50000
#define DIN   128

typedef short bf16x8 __attribute__((ext_vector_type(8)));
typedef float f32x4  __attribute__((ext_vector_type(4)));

union FragU { uint4 q; unsigned int u[4]; bf16x8 v; };

__device__ __forceinline__ unsigned int f2bf(float x) {
  // RNE fp32 -> bf16 bits (finite inputs only)
  unsigned int b = __float_as_uint(x);
  return ((b + 0x7fffu + ((b >> 16) & 1u)) >> 16) & 0xffffu;
}

__device__ __forceinline__ void async_cp16(const uint4* g, uint4* l) {
  // DMA 16B/lane global->LDS; LDS dest = wave-uniform base + lane*16 (m104)
  __builtin_amdgcn_global_load_lds((const __attribute__((address_space(1))) void*)g,
                                   (__attribute__((address_space(3))) void*)l, 16, 0, 0);
}

// ---------------- kernel 1: node l2norm -> bf16 table, fused weight prep ----------------
__global__ __launch_bounds__(256) void k_pre(const float* __restrict__ nf,
                                             const float* __restrict__ W1,
                                             const float* __restrict__ W2,
                                             unsigned short* __restrict__ nfb,
                                             unsigned int* __restrict__ B1,
                                             unsigned int* __restrict__ B2) {
  if (blockIdx.x < 6250) {                         // norm: 2 nodes/wave, 8/block
    const int wv = threadIdx.x >> 6, l = threadIdx.x & 63;
    const int h = l >> 5, r = l & 31;
    const int node = blockIdx.x * 8 + wv * 2 + h;  // 6250*8 = 50000 exactly
    const float4* row = (const float4*)(nf + (size_t)node * DIN);
    float4 v = row[r];
    float ss = v.x * v.x + v.y * v.y + v.z * v.z + v.w * v.w;
    #pragma unroll
    for (int msk = 1; msk < 32; msk <<= 1) ss += __shfl_xor(ss, msk);
    const float inv = 1.0f / (sqrtf(ss) + 1e-8f);  // matches reference x/(norm+1e-8)
    uint2 o;
    o.x = f2bf(v.x * inv) | (f2bf(v.y * inv) << 16);
    o.y = f2bf(v.z * inv) | (f2bf(v.w * inv) << 16);
    ((uint2*)(nfb + (size_t)node * DIN))[r] = o;
  } else {                                         // prep: B-fragment layout
    const int id = (blockIdx.x - 6250) * 256 + threadIdx.x;   // 96*256 = 24576
    if (id < 16384) {                              // B1: 8 K-steps (K=256)
      const int dw = id & 3, lane = (id >> 2) & 63, nt = (id >> 8) & 7, s = id >> 11;
      const int n = nt * 16 + (lane & 15);
      const int k0 = (lane >> 4) * 8 + s * 32 + dw * 2;
      B1[id] = f2bf(W1[n * 257 + k0]) | (f2bf(W1[n * 257 + k0 + 1]) << 16);
    } else {                                       // B2: 4 K-steps (K=128)
      const int i2 = id - 16384;
      const int dw = i2 & 3, lane = (i2 >> 2) & 63, nt = (i2 >> 8) & 7, s = i2 >> 11;
      const int n = nt * 16 + (lane & 15);
      const int k0 = (lane >> 4) * 8 + s * 32 + dw * 2;
      B2[i2] = f2bf(W2[n * 128 + k0]) | (f2bf(W2[n * 128 + k0 + 1]) << 16);
    }
  }
}

// ---------------- kernel 2: fused edge MLP ----------------
// block = 256 (4 waves), wave = 32 edges (2 M-tiles), grid = 4688 (last block half-tail).
// LDS: 2 x 8KB weight chunks (double-buffered DMA), 4 waves x 2 x 4KB swizzled h1 tiles.
__global__ __launch_bounds__(256, 3) void k_main(
    const unsigned short* __restrict__ nfb, const int* __restrict__ ei,
    const unsigned int* __restrict__ B1, const unsigned int* __restrict__ B2,
    const float* __restrict__ W1, const float* __restrict__ b1,
    const float* __restrict__ b2, const float* __restrict__ W3,
    const float* __restrict__ b3, float* __restrict__ out) {
  __shared__ unsigned int lds[4096 + 4 * 2048];    // 49,152 B
  const int tid = threadIdx.x;
  const int wv = tid >> 6, l = tid & 63, m = l & 15, a = l >> 4;
  char* sH0 = (char*)(lds + 4096) + wv * 8192;     // h1 tile 0 (16x128 bf16, swizzled)
  char* sH1 = sH0 + 4096;                          // h1 tile 1

  // --- edge_index dtype defense: int64 => odd 32-bit words are zero high-words
  const int w0 = ei[l];
  const bool is64 = __all((l & 1) == 0 || w0 == 0);

  const int e0 = blockIdx.x * 128 + wv * 32 + m;   // tile0 edge, tile1 = e0+16
  const int ec0 = min(e0, E_TOT - 1);
  const int ec1 = min(e0 + 16, E_TOT - 1);
  int ns0, nt0_, ns1, nt1_;
  if (is64) { ns0 = ei[2 * ec0]; nt0_ = ei[2 * (E_TOT + ec0)];
              ns1 = ei[2 * ec1]; nt1_ = ei[2 * (E_TOT + ec1)]; }
  else      { ns0 = ei[ec0];     nt0_ = ei[E_TOT + ec0];
              ns1 = ei[ec1];     nt1_ = ei[E_TOT + ec1]; }
  ns0 = min(max(ns0, 0), NN - 1);  nt0_ = min(max(nt0_, 0), NN - 1);
  ns1 = min(max(ns1, 0), NN - 1);  nt1_ = min(max(nt1_, 0), NN - 1);

  // --- gather A-frags: lane (a,m) holds dims {8a+32s..+7} of its edge (uint4 = 8 bf16)
  const uint4* rs0 = (const uint4*)(nfb + (size_t)ns0 * DIN);
  const uint4* rt0 = (const uint4*)(nfb + (size_t)nt0_ * DIN);
  const uint4* rs1 = (const uint4*)(nfb + (size_t)ns1 * DIN);
  const uint4* rt1 = (const uint4*)(nfb + (size_t)nt1_ * DIN);
  uint4 hsv0[4], htv0[4], hsv1[4], htv1[4];
  #pragma unroll
  for (int s = 0; s < 4; ++s) {
    hsv0[s] = rs0[a + 4 * s]; htv0[s] = rt0[a + 4 * s];
    hsv1[s] = rs1[a + 4 * s]; htv1[s] = rt1[a + 4 * s];
  }

  // --- dist per tile (fp32 from bf16), each lane owns 32 dims of its edge
  float dist_r0[4], dist_r1[4];
  {
    float dp0 = 0.f, dp1 = 0.f;
    #pragma unroll
    for (int i = 0; i < 4; ++i) {
      const unsigned int* h0u = (const unsigned int*)&hsv0[i];
      const unsigned int* t0u = (const unsigned int*)&htv0[i];
      const unsigned int* h1u = (const unsigned int*)&hsv1[i];
      const unsigned int* t1u = (const unsigned int*)&htv1[i];
      #pragma unroll
      for (int j = 0; j < 4; ++j) {
        float dlo = __uint_as_float(h0u[j] << 16) - __uint_as_float(t0u[j] << 16);
        float dhi = __uint_as_float(h0u[j] & 0xffff0000u) - __uint_as_float(t0u[j] & 0xffff0000u);
        dp0 = fmaf(dlo, dlo, dp0); dp0 = fmaf(dhi, dhi, dp0);
        float elo = __uint_as_float(h1u[j] << 16) - __uint_as_float(t1u[j] << 16);
        float ehi = __uint_as_float(h1u[j] & 0xffff0000u) - __uint_as_float(t1u[j] & 0xffff0000u);
        dp1 = fmaf(elo, elo, dp1); dp1 = fmaf(ehi, ehi, dp1);
      }
    }
    dp0 += __shfl_xor(dp0, 16); dp0 += __shfl_xor(dp0, 32);
    dp1 += __shfl_xor(dp1, 16); dp1 += __shfl_xor(dp1, 32);
    const float d0 = sqrtf(dp0), d1 = sqrtf(dp1);
    #pragma unroll
    for (int r = 0; r < 4; ++r) {                  // C rows 4a+r need dist of edge 4a+r
      dist_r0[r] = __shfl(d0, a * 4 + r);
      dist_r1[r] = __shfl(d1, a * 4 + r);
    }
  }

  f32x4 acc0[8], acc1[8];
  #pragma unroll
  for (int nt = 0; nt < 8; ++nt) {
    acc0[nt] = (f32x4){0.f, 0.f, 0.f, 0.f};
    acc1[nt] = (f32x4){0.f, 0.f, 0.f, 0.f};
  }

  // --- weight staging: 8KB chunk/step via global_load_lds, double-buffered
  const uint4* g1 = (const uint4*)B1;              // 4096 uint4 (8 chunks)
  const uint4* g2 = (const uint4*)B2;              // 2048 uint4 (4 chunks)
  uint4* sB0 = (uint4*)lds;                        // 512 uint4 each
  uint4* sB1b = sB0 + 512;

  #define STAGE(c) do {                                                      \
    const uint4* gs_ = ((c) < 8) ? (g1 + (c) * 512) : (g2 + ((c) - 8) * 512);\
    uint4* db_ = (((c) & 1) ? sB1b : sB0);                                   \
    async_cp16(gs_ + wv * 64 + l, db_ + wv * 64);                            \
    async_cp16(gs_ + 256 + wv * 64 + l, db_ + 256 + wv * 64);                \
  } while (0)

  STAGE(0);
  __syncthreads();                                 // drains vmcnt: chunk 0 visible

  #pragma unroll
  for (int st = 0; st < 12; ++st) {
    if (st < 11) STAGE(st + 1);                    // DMA next chunk under this compute

    FragU af0, af1;
    if (st < 4)      { af0.q = hsv0[st];     af1.q = hsv1[st]; }
    else if (st < 8) { af0.q = htv0[st - 4]; af1.q = htv1[st - 4]; }
    else {                                         // h1 A-frags from swizzled tiles
      const int s2 = st - 8;
      const int col = (16 * a + 64 * s2) ^ ((m & 7) << 4);
      af0.q = *(const uint4*)(sH0 + m * 256 + col);
      af1.q = *(const uint4*)(sH1 + m * 256 + col);
    }

    const uint4* sB = (st & 1) ? sB1b : sB0;
    #pragma unroll
    for (int nt = 0; nt < 8; ++nt) {
      FragU bfr; bfr.q = sB[nt * 64 + l];
      acc0[nt] = __builtin_amdgcn_mfma_f32_16x16x32_bf16(af0.v, bfr.v, acc0[nt], 0, 0, 0);
      acc1[nt] = __builtin_amdgcn_mfma_f32_16x16x32_bf16(af1.v, bfr.v, acc1[nt], 0, 0, 0);
    }

    if (st == 7) {                                 // layer-1 epilogue -> swizzled h1 tiles
      #pragma unroll
      for (int nt = 0; nt < 8; ++nt) {
        const int n = nt * 16 + m;
        const float b1v = b1[n];
        const float w1l = W1[n * 257 + 256];       // dist column of W1
        #pragma unroll
        for (int r = 0; r < 4; ++r) {
          const int row = 4 * a + r;
          const int cb = (2 * n) ^ ((row & 7) << 4);
          float v0 = fmaxf(acc0[nt][r] + b1v + w1l * dist_r0[r], 0.f);
          float v1 = fmaxf(acc1[nt][r] + b1v + w1l * dist_r1[r], 0.f);
          *(unsigned short*)(sH0 + row * 256 + cb) = (unsigned short)f2bf(v0);
          *(unsigned short*)(sH1 + row * 256 + cb) = (unsigned short)f2bf(v1);
        }
        acc0[nt] = (f32x4){0.f, 0.f, 0.f, 0.f};    // reuse as GEMM2 accumulators
        acc1[nt] = (f32x4){0.f, 0.f, 0.f, 0.f};
      }
    }
    __syncthreads();                               // next chunk visible; buffers rotate
  }

  // --- layer 3 + gate
  float p0[4] = {0.f, 0.f, 0.f, 0.f}, p1[4] = {0.f, 0.f, 0.f, 0.f};
  #pragma unroll
  for (int nt = 0; nt < 8; ++nt) {
    const int n = nt * 16 + m;
    const float b2v = b2[n];
    const float w3v = W3[n];
    #pragma unroll
    for (int r = 0; r < 4; ++r) {
      p0[r] = fmaf(fmaxf(acc0[nt][r] + b2v, 0.f), w3v, p0[r]);
      p1[r] = fmaf(fmaxf(acc1[nt][r] + b2v, 0.f), w3v, p1[r]);
    }
  }
  #pragma unroll
  for (int r = 0; r < 4; ++r) {
    #pragma unroll
    for (int msk = 1; msk < 16; msk <<= 1) {
      p0[r] += __shfl_xor(p0[r], msk);
      p1[r] += __shfl_xor(p1[r], msk);
    }
  }
  if (m == 0) {
    const float b3v = b3[0];
    #pragma unroll
    for (int t = 0; t < 2; ++t) {
      #pragma unroll
      for (int r = 0; r < 4; ++r) {
        const int eo = blockIdx.x * 128 + wv * 32 + t * 16 + a * 4 + r;
        if (eo < E_TOT) {
          const float la = (t ? p1[r] : p0[r]) + b3v;
          const float sg = 1.f / (1.f + __expf(-la));
          out[eo] = fminf(fmaxf(sg * 1.2f - 0.1f, 0.f), 1.f);
          out[E_TOT + eo] = la;
        }
      }
    }
  }
}

extern "C" void kernel_launch(void* const* d_in, const int* in_sizes, int n_in,
                              void* d_out, int out_size, void* d_ws, size_t ws_size,
                              hipStream_t stream) {
  const float* node_feat = (const float*)d_in[0];
  const int*   edge_idx  = (const int*)d_in[1];
  const float* W1 = (const float*)d_in[2];
  const float* b1 = (const float*)d_in[3];
  const float* W2 = (const float*)d_in[4];
  const float* b2 = (const float*)d_in[5];
  const float* W3 = (const float*)d_in[6];
  const float* b3 = (const float*)d_in[7];
  float* out = (float*)d_out;

  unsigned char* ws = (unsigned char*)d_ws;
  // requires ws_size >= 12,898,304 bytes
  unsigned short* nfb = (unsigned short*)(ws);                       // 12.8 MB
  unsigned int*   B1  = (unsigned int*)(ws + 12800000);              // 64 KB
  unsigned int*   B2  = (unsigned int*)(ws + 12800000 + 65536);      // 32 KB

  hipLaunchKernelGGL(k_pre, dim3(6346), dim3(256), 0, stream,
                     node_feat, W1, W2, nfb, B1, B2);
  hipLaunchKernelGGL(k_main, dim3(4688), dim3(256), 0, stream,
                     nfb, edge_idx, B1, B2, W1, b1, b2, W3, b3, out);
}

// Round 9
// 185.390 us; speedup vs baseline: 1.6818x; 1.0333x over previous
//
#include <hip/hip_runtime.h>

// EdgeScoringNetwork on MI355X (gfx950) — bf16 MFMA, 32 edges/wave.
//   nf = l2norm(node_feat); per edge: ef=[hs,ht,dist] -> relu(W1 ef+b1) -> relu(W2 h+b2) -> W3 h+b3
//   out[0..E) = clip(sigmoid(logA)*1.2-0.1, 0,1);  out[E..2E) = logA
// R9 == R7/R8 (never benched: GPU timeouts). (1) dist via MFMA dot-trick (dist=sqrt(2-2*hs.ht);
// hsv/htv regs double as A- and B-frags, diagonal extracted by shuffle) — kills the ~256-op
// VALU unpack loop; (2) dist column + b1 folded into GEMM1 as a 9th K-step (K=288) —
// layer-1 epilogue is relu+pack only.
// ws layout: [nfb 12.8MB][B1 72KB (9 steps)][B2 32KB]

#define E_TOT 600000
#define NN    50000
#define DIN   128

typedef short bf16x8 __attribute__((ext_vector_type(8)));
typedef float f32x4  __attribute__((ext_vector_type(4)));

union FragU { uint4 q; unsigned int u[4]; bf16x8 v; };

__device__ __forceinline__ unsigned int f2bf(float x) {
  // RNE fp32 -> bf16 bits (finite inputs only)
  unsigned int b = __float_as_uint(x);
  return ((b + 0x7fffu + ((b >> 16) & 1u)) >> 16) & 0xffffu;
}

__device__ __forceinline__ void async_cp16(const uint4* g, uint4* l) {
  // DMA 16B/lane global->LDS; LDS dest = wave-uniform base + lane*16 (m104)
  __builtin_amdgcn_global_load_lds((const __attribute__((address_space(1))) void*)g,
                                   (__attribute__((address_space(3))) void*)l, 16, 0, 0);
}

// ---------------- kernel 1: node l2norm -> bf16 table, fused weight prep ----------------
__global__ __launch_bounds__(256) void k_pre(const float* __restrict__ nf,
                                             const float* __restrict__ W1,
                                             const float* __restrict__ b1,
                                             const float* __restrict__ W2,
                                             unsigned short* __restrict__ nfb,
                                             unsigned int* __restrict__ B1,
                                             unsigned int* __restrict__ B2) {
  if (blockIdx.x < 6250) {                         // norm: 2 nodes/wave, 8/block
    const int wv = threadIdx.x >> 6, l = threadIdx.x & 63;
    const int h = l >> 5, r = l & 31;
    const int node = blockIdx.x * 8 + wv * 2 + h;  // 6250*8 = 50000 exactly
    const float4* row = (const float4*)(nf + (size_t)node * DIN);
    float4 v = row[r];
    float ss = v.x * v.x + v.y * v.y + v.z * v.z + v.w * v.w;
    #pragma unroll
    for (int msk = 1; msk < 32; msk <<= 1) ss += __shfl_xor(ss, msk);
    const float inv = 1.0f / (sqrtf(ss) + 1e-8f);  // matches reference x/(norm+1e-8)
    uint2 o;
    o.x = f2bf(v.x * inv) | (f2bf(v.y * inv) << 16);
    o.y = f2bf(v.z * inv) | (f2bf(v.w * inv) << 16);
    ((uint2*)(nfb + (size_t)node * DIN))[r] = o;
  } else {                                         // prep: B-fragment layout
    const int id = (blockIdx.x - 6250) * 256 + threadIdx.x;   // 104*256 = 26624
    if (id < 18432) {                              // B1: 9 K-steps (K=288 augmented)
      const int dw = id & 3, lane = (id >> 2) & 63, nt = (id >> 8) & 7, s = id >> 11;
      const int n = nt * 16 + (lane & 15);
      if (s < 8) {                                 // true W1 columns 0..255
        const int k0 = (lane >> 4) * 8 + s * 32 + dw * 2;
        B1[id] = f2bf(W1[n * 257 + k0]) | (f2bf(W1[n * 257 + k0 + 1]) << 16);
      } else {                                     // step 8: [dist_col, b1, 0...0]
        B1[id] = ((lane >> 4) == 0 && dw == 0)
                   ? (f2bf(W1[n * 257 + 256]) | (f2bf(b1[n]) << 16))
                   : 0u;
      }
    } else {                                       // B2: 4 K-steps (K=128)
      const int i2 = id - 18432;                   // < 8192
      const int dw = i2 & 3, lane = (i2 >> 2) & 63, nt = (i2 >> 8) & 7, s = i2 >> 11;
      const int n = nt * 16 + (lane & 15);
      const int k0 = (lane >> 4) * 8 + s * 32 + dw * 2;
      B2[i2] = f2bf(W2[n * 128 + k0]) | (f2bf(W2[n * 128 + k0 + 1]) << 16);
    }
  }
}

// ---------------- kernel 2: fused edge MLP ----------------
// block = 256 (4 waves), wave = 32 edges (2 M-tiles), grid = 4688 (last block half-tail).
// 13 K-steps: 9 GEMM1 (K=288 incl. dist/bias step) + 4 GEMM2.
// LDS: 2 x 8KB weight chunks (double-buffered DMA), 4 waves x 2 x 4KB swizzled h1 tiles.
__global__ __launch_bounds__(256, 3) void k_main(
    const unsigned short* __restrict__ nfb, const int* __restrict__ ei,
    const unsigned int* __restrict__ B1, const unsigned int* __restrict__ B2,
    const float* __restrict__ b2, const float* __restrict__ W3,
    const float* __restrict__ b3, float* __restrict__ out) {
  __shared__ unsigned int lds[4096 + 4 * 2048];    // 49,152 B
  const int tid = threadIdx.x;
  const int wv = tid >> 6, l = tid & 63, m = l & 15, a = l >> 4;
  char* sH0 = (char*)(lds + 4096) + wv * 8192;     // h1 tile 0 (16x128 bf16, swizzled)
  char* sH1 = sH0 + 4096;                          // h1 tile 1

  // --- edge_index dtype defense: int64 => odd 32-bit words are zero high-words
  const int w0 = ei[l];
  const bool is64 = __all((l & 1) == 0 || w0 == 0);

  const int e0 = blockIdx.x * 128 + wv * 32 + m;   // tile0 edge, tile1 = e0+16
  const int ec0 = min(e0, E_TOT - 1);
  const int ec1 = min(e0 + 16, E_TOT - 1);
  int ns0, nt0_, ns1, nt1_;
  if (is64) { ns0 = ei[2 * ec0]; nt0_ = ei[2 * (E_TOT + ec0)];
              ns1 = ei[2 * ec1]; nt1_ = ei[2 * (E_TOT + ec1)]; }
  else      { ns0 = ei[ec0];     nt0_ = ei[E_TOT + ec0];
              ns1 = ei[ec1];     nt1_ = ei[E_TOT + ec1]; }
  ns0 = min(max(ns0, 0), NN - 1);  nt0_ = min(max(nt0_, 0), NN - 1);
  ns1 = min(max(ns1, 0), NN - 1);  nt1_ = min(max(nt1_, 0), NN - 1);

  // --- gather A-frags: lane (a,m) holds dims {8a+32s..+7} of its edge (uint4 = 8 bf16)
  const uint4* rs0 = (const uint4*)(nfb + (size_t)ns0 * DIN);
  const uint4* rt0 = (const uint4*)(nfb + (size_t)nt0_ * DIN);
  const uint4* rs1 = (const uint4*)(nfb + (size_t)ns1 * DIN);
  const uint4* rt1 = (const uint4*)(nfb + (size_t)nt1_ * DIN);
  uint4 hsv0[4], htv0[4], hsv1[4], htv1[4];
  #pragma unroll
  for (int s = 0; s < 4; ++s) {
    hsv0[s] = rs0[a + 4 * s]; htv0[s] = rt0[a + 4 * s];
    hsv1[s] = rs1[a + 4 * s]; htv1[s] = rt1[a + 4 * s];
  }

  // --- dist via MFMA dot-trick: D[i][j] = hs_i . ht_j  (hsv doubles as A-frag, htv as
  // B-frag: identical per-lane content). Diagonal e at lane 16*(e>>2)+e, reg e&3.
  unsigned int dfw0, dfw1;                         // step-8 A-frag dword0 per tile
  {
    f32x4 ad0 = (f32x4){0.f, 0.f, 0.f, 0.f}, ad1 = (f32x4){0.f, 0.f, 0.f, 0.f};
    #pragma unroll
    for (int s = 0; s < 4; ++s) {
      FragU a0, b0, a1, b1f;
      a0.q = hsv0[s]; b0.q = htv0[s]; a1.q = hsv1[s]; b1f.q = htv1[s];
      ad0 = __builtin_amdgcn_mfma_f32_16x16x32_bf16(a0.v, b0.v, ad0, 0, 0, 0);
      ad1 = __builtin_amdgcn_mfma_f32_16x16x32_bf16(a1.v, b1f.v, ad1, 0, 0, 0);
    }
    const int srcl = 16 * (m >> 2) + m;            // diag holder for e = m
    float ds0[4], ds1[4];
    #pragma unroll
    for (int r = 0; r < 4; ++r) {
      ds0[r] = __shfl(ad0[r], srcl);
      ds1[r] = __shfl(ad1[r], srcl);
    }
    const float sel0 = (m & 2) ? ((m & 1) ? ds0[3] : ds0[2])
                               : ((m & 1) ? ds0[1] : ds0[0]);
    const float sel1 = (m & 2) ? ((m & 1) ? ds1[3] : ds1[2])
                               : ((m & 1) ? ds1[1] : ds1[0]);
    const float dist0 = sqrtf(fmaxf(2.f - 2.f * sel0, 0.f));
    const float dist1 = sqrtf(fmaxf(2.f - 2.f * sel1, 0.f));
    dfw0 = (a == 0) ? (f2bf(dist0) | 0x3F800000u) : 0u;   // (dist, 1.0) bf16 pair
    dfw1 = (a == 0) ? (f2bf(dist1) | 0x3F800000u) : 0u;
  }

  f32x4 acc0[8], acc1[8];
  #pragma unroll
  for (int nt = 0; nt < 8; ++nt) {
    acc0[nt] = (f32x4){0.f, 0.f, 0.f, 0.f};
    acc1[nt] = (f32x4){0.f, 0.f, 0.f, 0.f};
  }

  // --- weight staging: 8KB chunk/step via global_load_lds, double-buffered
  const uint4* g1 = (const uint4*)B1;              // 4608 uint4 (9 chunks)
  const uint4* g2 = (const uint4*)B2;              // 2048 uint4 (4 chunks)
  uint4* sB0 = (uint4*)lds;                        // 512 uint4 each
  uint4* sB1b = sB0 + 512;

  #define STAGE(c) do {                                                      \
    const uint4* gs_ = ((c) < 9) ? (g1 + (c) * 512) : (g2 + ((c) - 9) * 512);\
    uint4* db_ = (((c) & 1) ? sB1b : sB0);                                   \
    async_cp16(gs_ + wv * 64 + l, db_ + wv * 64);                            \
    async_cp16(gs_ + 256 + wv * 64 + l, db_ + 256 + wv * 64);                \
  } while (0)

  STAGE(0);
  __syncthreads();                                 // drains vmcnt: chunk 0 visible

  #pragma unroll
  for (int st = 0; st < 13; ++st) {
    if (st < 12) STAGE(st + 1);                    // DMA next chunk under this compute

    FragU af0, af1;
    if (st < 4)      { af0.q = hsv0[st];     af1.q = hsv1[st]; }
    else if (st < 8) { af0.q = htv0[st - 4]; af1.q = htv1[st - 4]; }
    else if (st == 8) {                            // augmented K-step: (dist, 1, 0...)
      af0.u[0] = dfw0; af0.u[1] = 0; af0.u[2] = 0; af0.u[3] = 0;
      af1.u[0] = dfw1; af1.u[1] = 0; af1.u[2] = 0; af1.u[3] = 0;
    } else {                                       // h1 A-frags from swizzled tiles
      const int s2 = st - 9;
      const int col = (16 * a + 64 * s2) ^ ((m & 7) << 4);
      af0.q = *(const uint4*)(sH0 + m * 256 + col);
      af1.q = *(const uint4*)(sH1 + m * 256 + col);
    }

    const uint4* sB = (st & 1) ? sB1b : sB0;
    #pragma unroll
    for (int nt = 0; nt < 8; ++nt) {
      FragU bfr; bfr.q = sB[nt * 64 + l];
      acc0[nt] = __builtin_amdgcn_mfma_f32_16x16x32_bf16(af0.v, bfr.v, acc0[nt], 0, 0, 0);
      acc1[nt] = __builtin_amdgcn_mfma_f32_16x16x32_bf16(af1.v, bfr.v, acc1[nt], 0, 0, 0);
    }

    if (st == 8) {                                 // layer-1 epilogue: relu + pack only
      #pragma unroll
      for (int nt = 0; nt < 8; ++nt) {
        const int n = nt * 16 + m;
        #pragma unroll
        for (int r = 0; r < 4; ++r) {
          const int row = 4 * a + r;
          const int cb = (2 * n) ^ ((row & 7) << 4);
          const float v0 = fmaxf(acc0[nt][r], 0.f);
          const float v1 = fmaxf(acc1[nt][r], 0.f);
          *(unsigned short*)(sH0 + row * 256 + cb) = (unsigned short)f2bf(v0);
          *(unsigned short*)(sH1 + row * 256 + cb) = (unsigned short)f2bf(v1);
        }
        acc0[nt] = (f32x4){0.f, 0.f, 0.f, 0.f};    // reuse as GEMM2 accumulators
        acc1[nt] = (f32x4){0.f, 0.f, 0.f, 0.f};
      }
    }
    __syncthreads();                               // next chunk visible; buffers rotate
  }

  // --- layer 3 + gate
  float p0[4] = {0.f, 0.f, 0.f, 0.f}, p1[4] = {0.f, 0.f, 0.f, 0.f};
  #pragma unroll
  for (int nt = 0; nt < 8; ++nt) {
    const int n = nt * 16 + m;
    const float b2v = b2[n];
    const float w3v = W3[n];
    #pragma unroll
    for (int r = 0; r < 4; ++r) {
      p0[r] = fmaf(fmaxf(acc0[nt][r] + b2v, 0.f), w3v, p0[r]);
      p1[r] = fmaf(fmaxf(acc1[nt][r] + b2v, 0.f), w3v, p1[r]);
    }
  }
  #pragma unroll
  for (int r = 0; r < 4; ++r) {
    #pragma unroll
    for (int msk = 1; msk < 16; msk <<= 1) {
      p0[r] += __shfl_xor(p0[r], msk);
      p1[r] += __shfl_xor(p1[r], msk);
    }
  }
  if (m == 0) {
    const float b3v = b3[0];
    #pragma unroll
    for (int t = 0; t < 2; ++t) {
      #pragma unroll
      for (int r = 0; r < 4; ++r) {
        const int eo = blockIdx.x * 128 + wv * 32 + t * 16 + a * 4 + r;
        if (eo < E_TOT) {
          const float la = (t ? p1[r] : p0[r]) + b3v;
          const float sg = 1.f / (1.f + __expf(-la));
          out[eo] = fminf(fmaxf(sg * 1.2f - 0.1f, 0.f), 1.f);
          out[E_TOT + eo] = la;
        }
      }
    }
  }
}

extern "C" void kernel_launch(void* const* d_in, const int* in_sizes, int n_in,
                              void* d_out, int out_size, void* d_ws, size_t ws_size,
                              hipStream_t stream) {
  const float* node_feat = (const float*)d_in[0];
  const int*   edge_idx  = (const int*)d_in[1];
  const float* W1 = (const float*)d_in[2];
  const float* b1 = (const float*)d_in[3];
  const float* W2 = (const float*)d_in[4];
  const float* b2 = (const float*)d_in[5];
  const float* W3 = (const float*)d_in[6];
  const float* b3 = (const float*)d_in[7];
  float* out = (float*)d_out;

  unsigned char* ws = (unsigned char*)d_ws;
  // requires ws_size >= 12,906,496 bytes
  unsigned short* nfb = (unsigned short*)(ws);                       // 12.8 MB
  unsigned int*   B1  = (unsigned int*)(ws + 12800000);              // 72 KB (9 chunks)
  unsigned int*   B2  = (unsigned int*)(ws + 12800000 + 73728);      // 32 KB

  hipLaunchKernelGGL(k_pre, dim3(6354), dim3(256), 0, stream,
                     node_feat, W1, b1, W2, nfb, B1, B2);
  hipLaunchKernelGGL(k_main, dim3(4688), dim3(256), 0, stream,
                     nfb, edge_idx, B1, B2, b2, W3, b3, out);
}